// Round 1
// baseline (1427.392 us; speedup 1.0000x reference)
//
#include <hip/hip_runtime.h>
#include <math.h>

#define N_NODES 40000
#define E_EDGES 640000
#define IN_DIM 128
#define EDGE_DIM 64
#define HID 128

// ---------------------------------------------------------------------------
// ws layout (floats):
//   P1   [N_NODES*HID]   : x @ Wn_w[:128,:] + (Wh_b + Wn_b)   (bias folded)
//   P2   [N_NODES*HID]   : x @ Wn_w[128:,:]
//   Wht  [HID*EDGE_DIM]  : Wh_w transposed ([h][k], contiguous k)
//   expS [E_EDGES]       : exp(score_e)
//   sumExp [1]           : sum of expS
// ---------------------------------------------------------------------------

__global__ __launch_bounds__(256) void k_init(float* __restrict__ out,
                                              float* __restrict__ sumExp) {
    int i = blockIdx.x * 256 + threadIdx.x;   // grid covers N*IN_DIM exactly
    out[i] = 0.0f;
    if (i == 0) sumExp[0] = 0.0f;
}

__global__ __launch_bounds__(256) void k_trans(const float* __restrict__ Wh,
                                               float* __restrict__ Wht) {
    int i = blockIdx.x * 256 + threadIdx.x;   // 8192 elements exactly
    int h = i / EDGE_DIM;
    int k = i % EDGE_DIM;
    Wht[i] = Wh[k * HID + h];
}

// P1[n][h] = sum_k x[n][k]*Wn[k][h] + Whb[h] + Wnb[h]
// P2[n][h] = sum_k x[n][k]*Wn[128+k][h]
__global__ __launch_bounds__(256) void k_proj(const float* __restrict__ x,
                                              const float* __restrict__ Wn,
                                              const float* __restrict__ Whb,
                                              const float* __restrict__ Wnb,
                                              float* __restrict__ P1,
                                              float* __restrict__ P2) {
    __shared__ float xs[16][IN_DIM];
    const int rowBase = blockIdx.x * 16;

    const float4* xsrc = (const float4*)(x + (size_t)rowBase * IN_DIM);
    float4* xd = (float4*)&xs[0][0];
    for (int i = threadIdx.x; i < 16 * IN_DIM / 4; i += 256) xd[i] = xsrc[i];
    __syncthreads();

    const int h  = threadIdx.x & 127;
    const int rg = threadIdx.x >> 7;   // 0/1 -> rows rg*8 .. rg*8+7

    float acc1[8], acc2[8];
#pragma unroll
    for (int r = 0; r < 8; ++r) { acc1[r] = 0.f; acc2[r] = 0.f; }

    for (int k = 0; k < IN_DIM; ++k) {
        float wa = Wn[k * HID + h];
        float wb = Wn[(IN_DIM + k) * HID + h];
#pragma unroll
        for (int r = 0; r < 8; ++r) {
            float xv = xs[rg * 8 + r][k];
            acc1[r] += xv * wa;
            acc2[r] += xv * wb;
        }
    }
    const float bias = Whb[h] + Wnb[h];
#pragma unroll
    for (int r = 0; r < 8; ++r) {
        int row = rowBase + rg * 8 + r;
        P1[(size_t)row * HID + h] = acc1[r] + bias;
        P2[(size_t)row * HID + h] = acc2[r];
    }
}

// One thread per edge. score = sum_h relu(P1[src][h]+P2[dst][h]+ea.Wh[:,h]) * we[h]
__global__ __launch_bounds__(256) void k_edge(const int* __restrict__ eidx,
                                              const float* __restrict__ ea,
                                              const float* __restrict__ Wht,
                                              const float* __restrict__ P1,
                                              const float* __restrict__ P2,
                                              const float* __restrict__ we,
                                              float* __restrict__ expS,
                                              float* __restrict__ sumExp) {
    const int e = blockIdx.x * 256 + threadIdx.x;   // grid covers E exactly

    int src = eidx[e];
    int dst = eidx[E_EDGES + e];
    src = min(max(src, 0), N_NODES - 1);
    dst = min(max(dst, 0), N_NODES - 1);

    float ear[EDGE_DIM];
    const float4* ea4 = (const float4*)(ea + (size_t)e * EDGE_DIM);
#pragma unroll
    for (int i = 0; i < EDGE_DIM / 4; ++i) {
        float4 v = ea4[i];
        ear[4 * i + 0] = v.x; ear[4 * i + 1] = v.y;
        ear[4 * i + 2] = v.z; ear[4 * i + 3] = v.w;
    }

    const float4* p1r = (const float4*)(P1 + (size_t)src * HID);
    const float4* p2r = (const float4*)(P2 + (size_t)dst * HID);

    float s = 0.0f;
    for (int hc = 0; hc < HID / 4; ++hc) {
        float4 p1 = p1r[hc];
        float4 p2 = p2r[hc];
        float base[4] = { p1.x + p2.x, p1.y + p2.y, p1.z + p2.z, p1.w + p2.w };
#pragma unroll
        for (int j = 0; j < 4; ++j) {
            int h = hc * 4 + j;
            float acc = base[j];
            const float* wrow = Wht + h * EDGE_DIM;   // wave-uniform address
#pragma unroll
            for (int k = 0; k < EDGE_DIM; ++k) acc += ear[k] * wrow[k];
            acc = fmaxf(acc, 0.0f);
            s += acc * we[h];
        }
    }

    float ex = expf(s);
    expS[e] = ex;

    // wave-level reduction of sum(exp), one atomic per wave
    float v = ex;
#pragma unroll
    for (int off = 32; off > 0; off >>= 1) v += __shfl_down(v, off, 64);
    if ((threadIdx.x & 63) == 0) atomicAdd(sumExp, v);
}

// One wave per edge: out[src][:] += -alpha_e * x[dst][:]
__global__ __launch_bounds__(256) void k_scatter(const int* __restrict__ eidx,
                                                 const float* __restrict__ x,
                                                 const float* __restrict__ expS,
                                                 const float* __restrict__ sumExp,
                                                 float* __restrict__ out) {
    const float invS = 1.0f / sumExp[0];
    const int lane = threadIdx.x & 63;
    const int wid  = (blockIdx.x * 256 + threadIdx.x) >> 6;
    const int nw   = gridDim.x * 4;

    for (int e = wid; e < E_EDGES; e += nw) {
        int src = eidx[e];
        int dst = eidx[E_EDGES + e];
        src = min(max(src, 0), N_NODES - 1);
        dst = min(max(dst, 0), N_NODES - 1);
        float a = -expS[e] * invS;
        const float2* xr = (const float2*)(x + (size_t)dst * IN_DIM);
        float2 v = xr[lane];
        float* op = out + (size_t)src * IN_DIM + 2 * lane;
        atomicAdd(op + 0, a * v.x);
        atomicAdd(op + 1, a * v.y);
    }
}

// out[n] = y + y@ft + ftb, y = x + local(out). In-place safe (row-block LDS stage).
__global__ __launch_bounds__(256) void k_final(const float* __restrict__ x,
                                               const float* __restrict__ ft,
                                               const float* __restrict__ ftb,
                                               float* __restrict__ out) {
    __shared__ float ys[16][IN_DIM];
    const int rowBase = blockIdx.x * 16;

    const float4* xsrc = (const float4*)(x + (size_t)rowBase * IN_DIM);
    const float4* lsrc = (const float4*)(out + (size_t)rowBase * IN_DIM);
    float4* yd = (float4*)&ys[0][0];
    for (int i = threadIdx.x; i < 16 * IN_DIM / 4; i += 256) {
        float4 a = xsrc[i];
        float4 b = lsrc[i];
        a.x += b.x; a.y += b.y; a.z += b.z; a.w += b.w;
        yd[i] = a;
    }
    __syncthreads();

    const int h  = threadIdx.x & 127;
    const int rg = threadIdx.x >> 7;

    float acc[8];
#pragma unroll
    for (int r = 0; r < 8; ++r) acc[r] = 0.f;

    for (int k = 0; k < IN_DIM; ++k) {
        float w = ft[k * IN_DIM + h];
#pragma unroll
        for (int r = 0; r < 8; ++r) acc[r] += ys[rg * 8 + r][k] * w;
    }
    const float b = ftb[h];
#pragma unroll
    for (int r = 0; r < 8; ++r) {
        int row = rowBase + rg * 8 + r;
        out[(size_t)row * IN_DIM + h] = ys[rg * 8 + r][h] + acc[r] + b;
    }
}

extern "C" void kernel_launch(void* const* d_in, const int* in_sizes, int n_in,
                              void* d_out, int out_size, void* d_ws, size_t ws_size,
                              hipStream_t stream) {
    const float* x    = (const float*)d_in[0];
    const int*   eidx = (const int*)d_in[1];
    const float* ea   = (const float*)d_in[2];
    const float* Whw  = (const float*)d_in[3];
    const float* Whb  = (const float*)d_in[4];
    const float* Wnw  = (const float*)d_in[5];
    const float* Wnb  = (const float*)d_in[6];
    const float* we   = (const float*)d_in[7];
    const float* ftw  = (const float*)d_in[8];
    const float* ftb  = (const float*)d_in[9];
    float* out = (float*)d_out;

    float* P1     = (float*)d_ws;
    float* P2     = P1 + (size_t)N_NODES * HID;
    float* Wht    = P2 + (size_t)N_NODES * HID;
    float* expS   = Wht + (size_t)EDGE_DIM * HID;
    float* sumExp = expS + (size_t)E_EDGES;

    k_init   <<<(N_NODES * IN_DIM) / 256, 256, 0, stream>>>(out, sumExp);
    k_trans  <<<(EDGE_DIM * HID) / 256, 256, 0, stream>>>(Whw, Wht);
    k_proj   <<<N_NODES / 16, 256, 0, stream>>>(x, Wnw, Whb, Wnb, P1, P2);
    k_edge   <<<E_EDGES / 256, 256, 0, stream>>>(eidx, ea, Wht, P1, P2, we, expS, sumExp);
    k_scatter<<<2500, 256, 0, stream>>>(eidx, x, expS, sumExp, out);
    k_final  <<<N_NODES / 16, 256, 0, stream>>>(x, ftw, ftb, out);
}

// Round 2
// 1362.716 us; speedup vs baseline: 1.0475x; 1.0475x over previous
//
#include <hip/hip_runtime.h>
#include <math.h>

#define N_NODES 40000
#define E_EDGES 640000
#define IN_DIM 128
#define EDGE_DIM 64
#define HID 128

typedef unsigned int u32;
typedef unsigned short u16;

// bf16 helpers (bit-level, no header dependence)
__device__ __forceinline__ float bf_lo(u32 d) { return __uint_as_float(d << 16); }
__device__ __forceinline__ float bf_hi(u32 d) { return __uint_as_float(d & 0xffff0000u); }
__device__ __forceinline__ u16 f2bf(float f) {            // RNE
    u32 u = __float_as_uint(f);
    return (u16)((u + 0x7fffu + ((u >> 16) & 1u)) >> 16);
}

// ---------------------------------------------------------------------------
// ws layout:
//   P1b  [N*HID] u16 : bf16( x @ Wn[:128] + Whb + Wnb )
//   P2b  [N*HID] u16 : bf16( x @ Wn[128:] )
//   xb   [N*IN]  u16 : bf16(x)
//   Wht  [HID*EDGE_DIM] f32 (transposed, [h][k])
//   expS [E] f32
//   sumExp [1] f32
// ---------------------------------------------------------------------------

__global__ __launch_bounds__(256) void k_init(const float* __restrict__ x,
                                              float* __restrict__ out,
                                              u16* __restrict__ xb,
                                              float* __restrict__ sumExp) {
    int i = blockIdx.x * 256 + threadIdx.x;   // covers N*IN_DIM exactly
    out[i] = 0.0f;
    xb[i] = f2bf(x[i]);
    if (i == 0) sumExp[0] = 0.0f;
}

__global__ __launch_bounds__(256) void k_trans(const float* __restrict__ Wh,
                                               float* __restrict__ Wht) {
    int i = blockIdx.x * 256 + threadIdx.x;   // 8192 exactly
    int h = i / EDGE_DIM;
    int k = i % EDGE_DIM;
    Wht[i] = Wh[k * HID + h];
}

__global__ __launch_bounds__(256) void k_proj(const float* __restrict__ x,
                                              const float* __restrict__ Wn,
                                              const float* __restrict__ Whb,
                                              const float* __restrict__ Wnb,
                                              u16* __restrict__ P1b,
                                              u16* __restrict__ P2b) {
    __shared__ float xs[16][IN_DIM];
    const int rowBase = blockIdx.x * 16;

    const float4* xsrc = (const float4*)(x + (size_t)rowBase * IN_DIM);
    float4* xd = (float4*)&xs[0][0];
    for (int i = threadIdx.x; i < 16 * IN_DIM / 4; i += 256) xd[i] = xsrc[i];
    __syncthreads();

    const int h  = threadIdx.x & 127;
    const int rg = threadIdx.x >> 7;

    float acc1[8], acc2[8];
#pragma unroll
    for (int r = 0; r < 8; ++r) { acc1[r] = 0.f; acc2[r] = 0.f; }

    for (int k = 0; k < IN_DIM; ++k) {
        float wa = Wn[k * HID + h];
        float wb = Wn[(IN_DIM + k) * HID + h];
#pragma unroll
        for (int r = 0; r < 8; ++r) {
            float xv = xs[rg * 8 + r][k];
            acc1[r] += xv * wa;
            acc2[r] += xv * wb;
        }
    }
    const float bias = Whb[h] + Wnb[h];
#pragma unroll
    for (int r = 0; r < 8; ++r) {
        int row = rowBase + rg * 8 + r;
        P1b[(size_t)row * HID + h] = f2bf(acc1[r] + bias);
        P2b[(size_t)row * HID + h] = f2bf(acc2[r]);
    }
}

// One thread per edge, ear[64] held in VGPRs (launch_bounds(256,2) -> 256 VGPR cap).
// Gathered P rows read bf16 as two 128-B half-rows of 8 consecutive uint4 loads
// -> whole cache lines, fully consumed.
__global__ __launch_bounds__(256, 2) void k_edge(const int* __restrict__ eidx,
                                                 const float* __restrict__ ea,
                                                 const float* __restrict__ Wht,
                                                 const u16* __restrict__ P1b,
                                                 const u16* __restrict__ P2b,
                                                 const float* __restrict__ we,
                                                 float* __restrict__ expS,
                                                 float* __restrict__ sumExp) {
    const int e = blockIdx.x * 256 + threadIdx.x;   // grid covers E exactly

    int src = eidx[e];
    int dst = eidx[E_EDGES + e];
    src = min(max(src, 0), N_NODES - 1);
    dst = min(max(dst, 0), N_NODES - 1);

    float ear[EDGE_DIM];
    const float4* ea4 = (const float4*)(ea + (size_t)e * EDGE_DIM);
#pragma unroll
    for (int i = 0; i < EDGE_DIM / 4; ++i) {
        float4 v = ea4[i];
        ear[4 * i + 0] = v.x; ear[4 * i + 1] = v.y;
        ear[4 * i + 2] = v.z; ear[4 * i + 3] = v.w;
    }

    const uint4* p1q = (const uint4*)(P1b + (size_t)src * HID);
    const uint4* p2q = (const uint4*)(P2b + (size_t)dst * HID);

    float s = 0.0f;
    for (int half = 0; half < 2; ++half) {
        uint4 pa[8], pb[8];
#pragma unroll
        for (int q = 0; q < 8; ++q) {
            pa[q] = p1q[half * 8 + q];
            pb[q] = p2q[half * 8 + q];
        }
#pragma unroll
        for (int q = 0; q < 8; ++q) {
            u32 da[4] = { pa[q].x, pa[q].y, pa[q].z, pa[q].w };
            u32 db[4] = { pb[q].x, pb[q].y, pb[q].z, pb[q].w };
#pragma unroll
            for (int c = 0; c < 4; ++c) {
                const int h0 = (half << 6) + (q << 3) + (c << 1);
                float a0 = bf_lo(da[c]) + bf_lo(db[c]);
                float a1 = bf_hi(da[c]) + bf_hi(db[c]);
                const float* w0 = Wht + (h0 << 6);     // wave-uniform -> s_load
#pragma unroll
                for (int k = 0; k < EDGE_DIM; ++k) {
                    a0 = fmaf(ear[k], w0[k], a0);
                    a1 = fmaf(ear[k], w0[EDGE_DIM + k], a1);
                }
                s += fmaxf(a0, 0.0f) * we[h0] + fmaxf(a1, 0.0f) * we[h0 + 1];
            }
        }
    }

    float ex = __expf(s);
    expS[e] = ex;

    float v = ex;
#pragma unroll
    for (int off = 32; off > 0; off >>= 1) v += __shfl_down(v, off, 64);
    if ((threadIdx.x & 63) == 0) atomicAdd(sumExp, v);
}

// One wave per edge: out[src][:] += -alpha_e * x[dst][:]  (x read as bf16)
__global__ __launch_bounds__(256) void k_scatter(const int* __restrict__ eidx,
                                                 const u16* __restrict__ xb,
                                                 const float* __restrict__ expS,
                                                 const float* __restrict__ sumExp,
                                                 float* __restrict__ out) {
    const float invS = 1.0f / sumExp[0];
    const int lane = threadIdx.x & 63;
    const int wid  = (blockIdx.x * 256 + threadIdx.x) >> 6;
    const int nw   = gridDim.x * 4;

    for (int e = wid; e < E_EDGES; e += nw) {
        int src = eidx[e];
        int dst = eidx[E_EDGES + e];
        src = min(max(src, 0), N_NODES - 1);
        dst = min(max(dst, 0), N_NODES - 1);
        float a = -expS[e] * invS;
        const u32* xr = (const u32*)(xb + (size_t)dst * IN_DIM);
        u32 d = xr[lane];                                   // h = 2*lane, 2*lane+1
        float* op = out + (size_t)src * IN_DIM + 2 * lane;
        atomicAdd(op + 0, a * bf_lo(d));
        atomicAdd(op + 1, a * bf_hi(d));
    }
}

// out[n] = y + y@ft + ftb, y = x + local(out). fp32 throughout.
__global__ __launch_bounds__(256) void k_final(const float* __restrict__ x,
                                               const float* __restrict__ ft,
                                               const float* __restrict__ ftb,
                                               float* __restrict__ out) {
    __shared__ float ys[16][IN_DIM];
    const int rowBase = blockIdx.x * 16;

    const float4* xsrc = (const float4*)(x + (size_t)rowBase * IN_DIM);
    const float4* lsrc = (const float4*)(out + (size_t)rowBase * IN_DIM);
    float4* yd = (float4*)&ys[0][0];
    for (int i = threadIdx.x; i < 16 * IN_DIM / 4; i += 256) {
        float4 a = xsrc[i];
        float4 b = lsrc[i];
        a.x += b.x; a.y += b.y; a.z += b.z; a.w += b.w;
        yd[i] = a;
    }
    __syncthreads();

    const int h  = threadIdx.x & 127;
    const int rg = threadIdx.x >> 7;

    float acc[8];
#pragma unroll
    for (int r = 0; r < 8; ++r) acc[r] = 0.f;

    for (int k = 0; k < IN_DIM; ++k) {
        float w = ft[k * IN_DIM + h];
#pragma unroll
        for (int r = 0; r < 8; ++r) acc[r] += ys[rg * 8 + r][k] * w;
    }
    const float b = ftb[h];
#pragma unroll
    for (int r = 0; r < 8; ++r) {
        int row = rowBase + rg * 8 + r;
        out[(size_t)row * IN_DIM + h] = ys[rg * 8 + r][h] + acc[r] + b;
    }
}

extern "C" void kernel_launch(void* const* d_in, const int* in_sizes, int n_in,
                              void* d_out, int out_size, void* d_ws, size_t ws_size,
                              hipStream_t stream) {
    const float* x    = (const float*)d_in[0];
    const int*   eidx = (const int*)d_in[1];
    const float* ea   = (const float*)d_in[2];
    const float* Whw  = (const float*)d_in[3];
    const float* Whb  = (const float*)d_in[4];
    const float* Wnw  = (const float*)d_in[5];
    const float* Wnb  = (const float*)d_in[6];
    const float* we   = (const float*)d_in[7];
    const float* ftw  = (const float*)d_in[8];
    const float* ftb  = (const float*)d_in[9];
    float* out = (float*)d_out;

    u16*   P1b    = (u16*)d_ws;
    u16*   P2b    = P1b + (size_t)N_NODES * HID;
    u16*   xb     = P2b + (size_t)N_NODES * HID;
    float* Wht    = (float*)(xb + (size_t)N_NODES * IN_DIM);
    float* expS   = Wht + (size_t)EDGE_DIM * HID;
    float* sumExp = expS + (size_t)E_EDGES;

    k_init   <<<(N_NODES * IN_DIM) / 256, 256, 0, stream>>>(x, out, xb, sumExp);
    k_trans  <<<(EDGE_DIM * HID) / 256, 256, 0, stream>>>(Whw, Wht);
    k_proj   <<<N_NODES / 16, 256, 0, stream>>>(x, Wnw, Whb, Wnb, P1b, P2b);
    k_edge   <<<E_EDGES / 256, 256, 0, stream>>>(eidx, ea, Wht, P1b, P2b, we, expS, sumExp);
    k_scatter<<<2500, 256, 0, stream>>>(eidx, xb, expS, sumExp, out);
    k_final  <<<N_NODES / 16, 256, 0, stream>>>(x, ftw, ftb, out);
}

// Round 3
// 959.758 us; speedup vs baseline: 1.4872x; 1.4199x over previous
//
#include <hip/hip_runtime.h>
#include <math.h>

#define N_NODES 40000
#define E_EDGES 640000
#define IN_DIM 128
#define EDGE_DIM 64
#define HID 128
#define EB 10000   // edge blocks for k_edge (E/64)

typedef unsigned int u32;
typedef unsigned short u16;
typedef __attribute__((ext_vector_type(4))) float f32x4;
typedef __attribute__((ext_vector_type(8))) short bf16x8;

__device__ __forceinline__ float bf_lo(u32 d) { return __uint_as_float(d << 16); }
__device__ __forceinline__ float bf_hi(u32 d) { return __uint_as_float(d & 0xffff0000u); }
__device__ __forceinline__ u16 f2bf(float f) {            // RNE
    u32 u = __float_as_uint(f);
    return (u16)((u + 0x7fffu + ((u >> 16) & 1u)) >> 16);
}

// ---------------------------------------------------------------------------
// ws layout:
//   P1b  [N*HID] u16 : bf16( x @ Wn[:128] + Whb + Wnb )
//   P2b  [N*HID] u16 : bf16( x @ Wn[128:] )
//   xb   [N*IN]  u16 : bf16(x)
//   Whtb [HID*EDGE_DIM] u16 : bf16(Wh_w) transposed, [h][k]
//   expS [E] f32
//   partials [EB] f32 (per-block exp sums)
//   sumExp [1] f32
// ---------------------------------------------------------------------------

__global__ __launch_bounds__(256) void k_init(const float* __restrict__ x,
                                              float* __restrict__ out,
                                              u16* __restrict__ xb) {
    int i = blockIdx.x * 256 + threadIdx.x;   // covers N*IN_DIM exactly
    out[i] = 0.0f;
    xb[i] = f2bf(x[i]);
}

__global__ __launch_bounds__(256) void k_trans(const float* __restrict__ Wh,
                                               u16* __restrict__ Whtb) {
    int i = blockIdx.x * 256 + threadIdx.x;   // 8192 exactly
    int h = i >> 6;
    int k = i & 63;
    Whtb[i] = f2bf(Wh[k * HID + h]);
}

__global__ __launch_bounds__(256) void k_proj(const float* __restrict__ x,
                                              const float* __restrict__ Wn,
                                              const float* __restrict__ Whb,
                                              const float* __restrict__ Wnb,
                                              u16* __restrict__ P1b,
                                              u16* __restrict__ P2b) {
    __shared__ float xs[16][IN_DIM];
    const int rowBase = blockIdx.x * 16;

    const float4* xsrc = (const float4*)(x + (size_t)rowBase * IN_DIM);
    float4* xd = (float4*)&xs[0][0];
    for (int i = threadIdx.x; i < 16 * IN_DIM / 4; i += 256) xd[i] = xsrc[i];
    __syncthreads();

    const int h  = threadIdx.x & 127;
    const int rg = threadIdx.x >> 7;

    float acc1[8], acc2[8];
#pragma unroll
    for (int r = 0; r < 8; ++r) { acc1[r] = 0.f; acc2[r] = 0.f; }

    for (int k = 0; k < IN_DIM; ++k) {
        float wa = Wn[k * HID + h];
        float wb = Wn[(IN_DIM + k) * HID + h];
#pragma unroll
        for (int r = 0; r < 8; ++r) {
            float xv = xs[rg * 8 + r][k];
            acc1[r] += xv * wa;
            acc2[r] += xv * wb;
        }
    }
    const float bias = Whb[h] + Wnb[h];
#pragma unroll
    for (int r = 0; r < 8; ++r) {
        int row = rowBase + rg * 8 + r;
        P1b[(size_t)row * HID + h] = f2bf(acc1[r] + bias);
        P2b[(size_t)row * HID + h] = f2bf(acc2[r]);
    }
}

// MFMA edge kernel: block = 64 edges, 4 waves; wave w = m-tile of 16 edges.
// score[e] = sum_h relu( (ea@Wh)[e][h] + P1[src][h] + P2[dst][h] ) * we[h]
__global__ __launch_bounds__(256) void k_edge(const int* __restrict__ eidx,
                                              const float* __restrict__ ea,
                                              const u16* __restrict__ Whtb,
                                              const u16* __restrict__ P1b,
                                              const u16* __restrict__ P2b,
                                              const float* __restrict__ we,
                                              float* __restrict__ expS,
                                              float* __restrict__ partials) {
    __shared__ float Ps[64][132];   // +4 pad: 2-way banks on C-layout reads
    __shared__ float wsumLds[4];
    const int e0 = blockIdx.x * 64;
    const int t = threadIdx.x;

    // --- gather node term into LDS: Psum[m][:] = P1[src_m] + P2[dst_m] ---
    {
        const int m = t >> 2, c4 = t & 3;     // 4 threads per edge, 32 cols each
        int src = eidx[e0 + m];
        int dst = eidx[E_EDGES + e0 + m];
        const uint4* p1 = (const uint4*)(P1b + (size_t)src * HID + c4 * 32);
        const uint4* p2 = (const uint4*)(P2b + (size_t)dst * HID + c4 * 32);
#pragma unroll
        for (int i = 0; i < 4; ++i) {
            uint4 ua = p1[i], ub = p2[i];
            u32 da[4] = {ua.x, ua.y, ua.z, ua.w};
            u32 db[4] = {ub.x, ub.y, ub.z, ub.w};
#pragma unroll
            for (int j = 0; j < 4; ++j) {
                Ps[m][c4 * 32 + i * 8 + 2 * j]     = bf_lo(da[j]) + bf_lo(db[j]);
                Ps[m][c4 * 32 + i * 8 + 2 * j + 1] = bf_hi(da[j]) + bf_hi(db[j]);
            }
        }
    }
    __syncthreads();

    const int w = t >> 6, lane = t & 63;
    const int mrow = lane & 15, quad = lane >> 4;
    const int mt = w;

    // --- A fragments (f32 -> bf16 on the fly): A[m=lane&15][k=quad*8+j] ---
    const float* arow = ea + (size_t)(e0 + mt * 16 + mrow) * EDGE_DIM + quad * 8;
    bf16x8 a0, a1;
#pragma unroll
    for (int ks = 0; ks < 2; ++ks) {
        float4 f0 = *(const float4*)(arow + ks * 32);
        float4 f1 = *(const float4*)(arow + ks * 32 + 4);
        bf16x8& af = ks ? a1 : a0;
        af[0] = (short)f2bf(f0.x); af[1] = (short)f2bf(f0.y);
        af[2] = (short)f2bf(f0.z); af[3] = (short)f2bf(f0.w);
        af[4] = (short)f2bf(f1.x); af[5] = (short)f2bf(f1.y);
        af[6] = (short)f2bf(f1.z); af[7] = (short)f2bf(f1.w);
    }

    // --- MFMA over 8 n-tiles, K=64 in 2 steps; fuse +Psum, relu, *we ---
    float wsum[4] = {0.f, 0.f, 0.f, 0.f};
    const u16* bbase = Whtb + (size_t)mrow * EDGE_DIM + quad * 8;  // n = lane&15
#pragma unroll
    for (int nt = 0; nt < 8; ++nt) {
        const u16* bp = bbase + nt * 16 * EDGE_DIM;
        bf16x8 b0 = *(const bf16x8*)(bp);         // k = quad*8..+7
        bf16x8 b1 = *(const bf16x8*)(bp + 32);    // k = 32+quad*8..+7
        f32x4 c = {0.f, 0.f, 0.f, 0.f};
        c = __builtin_amdgcn_mfma_f32_16x16x32_bf16(a0, b0, c, 0, 0, 0);
        c = __builtin_amdgcn_mfma_f32_16x16x32_bf16(a1, b1, c, 0, 0, 0);
        float wv = we[nt * 16 + mrow];
#pragma unroll
        for (int r = 0; r < 4; ++r) {
            float v = c[r] + Ps[mt * 16 + quad * 4 + r][nt * 16 + mrow];
            wsum[r] += fmaxf(v, 0.f) * wv;
        }
    }

    // --- row sums across the 16 lanes of each quad group ---
#pragma unroll
    for (int off = 1; off < 16; off <<= 1) {
#pragma unroll
        for (int r = 0; r < 4; ++r) wsum[r] += __shfl_xor(wsum[r], off, 16);
    }
    float ex[4]; float s4 = 0.f;
#pragma unroll
    for (int r = 0; r < 4; ++r) { ex[r] = __expf(wsum[r]); s4 += ex[r]; }
    if (mrow == 0) {
#pragma unroll
        for (int r = 0; r < 4; ++r) expS[e0 + mt * 16 + quad * 4 + r] = ex[r];
    }
    // wave total of exp (each 16-lane group holds its 4 rows' sum)
    s4 += __shfl_xor(s4, 16, 64);
    s4 += __shfl_xor(s4, 32, 64);
    if (lane == 0) wsumLds[w] = s4;
    __syncthreads();
    if (t == 0) partials[blockIdx.x] = wsumLds[0] + wsumLds[1] + wsumLds[2] + wsumLds[3];
}

__global__ __launch_bounds__(256) void k_sum(const float* __restrict__ partials,
                                             float* __restrict__ sumExp) {
    float s = 0.f;
    for (int i = threadIdx.x; i < EB; i += 256) s += partials[i];
#pragma unroll
    for (int off = 1; off < 64; off <<= 1) s += __shfl_xor(s, off, 64);
    __shared__ float ws4[4];
    if ((threadIdx.x & 63) == 0) ws4[threadIdx.x >> 6] = s;
    __syncthreads();
    if (threadIdx.x == 0) sumExp[0] = ws4[0] + ws4[1] + ws4[2] + ws4[3];
}

// One wave per edge: out[src][:] += -alpha_e * x[dst][:]  (x read as bf16)
__global__ __launch_bounds__(256) void k_scatter(const int* __restrict__ eidx,
                                                 const u16* __restrict__ xb,
                                                 const float* __restrict__ expS,
                                                 const float* __restrict__ sumExp,
                                                 float* __restrict__ out) {
    const float invS = 1.0f / sumExp[0];
    const int lane = threadIdx.x & 63;
    const int wid  = (blockIdx.x * 256 + threadIdx.x) >> 6;
    const int nw   = gridDim.x * 4;

    for (int e = wid; e < E_EDGES; e += nw) {
        int src = eidx[e];
        int dst = eidx[E_EDGES + e];
        float a = -expS[e] * invS;
        const u32* xr = (const u32*)(xb + (size_t)dst * IN_DIM);
        u32 d = xr[lane];                                   // h = 2*lane, 2*lane+1
        float* op = out + (size_t)src * IN_DIM + 2 * lane;
        atomicAdd(op + 0, a * bf_lo(d));
        atomicAdd(op + 1, a * bf_hi(d));
    }
}

// out[n] = y + y@ft + ftb, y = x + local(out). fp32 throughout.
__global__ __launch_bounds__(256) void k_final(const float* __restrict__ x,
                                               const float* __restrict__ ft,
                                               const float* __restrict__ ftb,
                                               float* __restrict__ out) {
    __shared__ float ys[16][IN_DIM];
    const int rowBase = blockIdx.x * 16;

    const float4* xsrc = (const float4*)(x + (size_t)rowBase * IN_DIM);
    const float4* lsrc = (const float4*)(out + (size_t)rowBase * IN_DIM);
    float4* yd = (float4*)&ys[0][0];
    for (int i = threadIdx.x; i < 16 * IN_DIM / 4; i += 256) {
        float4 a = xsrc[i];
        float4 b = lsrc[i];
        a.x += b.x; a.y += b.y; a.z += b.z; a.w += b.w;
        yd[i] = a;
    }
    __syncthreads();

    const int h  = threadIdx.x & 127;
    const int rg = threadIdx.x >> 7;

    float acc[8];
#pragma unroll
    for (int r = 0; r < 8; ++r) acc[r] = 0.f;

    for (int k = 0; k < IN_DIM; ++k) {
        float w = ft[k * IN_DIM + h];
#pragma unroll
        for (int r = 0; r < 8; ++r) acc[r] += ys[rg * 8 + r][k] * w;
    }
    const float b = ftb[h];
#pragma unroll
    for (int r = 0; r < 8; ++r) {
        int row = rowBase + rg * 8 + r;
        out[(size_t)row * IN_DIM + h] = ys[rg * 8 + r][h] + acc[r] + b;
    }
}

extern "C" void kernel_launch(void* const* d_in, const int* in_sizes, int n_in,
                              void* d_out, int out_size, void* d_ws, size_t ws_size,
                              hipStream_t stream) {
    const float* x    = (const float*)d_in[0];
    const int*   eidx = (const int*)d_in[1];
    const float* ea   = (const float*)d_in[2];
    const float* Whw  = (const float*)d_in[3];
    const float* Whb  = (const float*)d_in[4];
    const float* Wnw  = (const float*)d_in[5];
    const float* Wnb  = (const float*)d_in[6];
    const float* we   = (const float*)d_in[7];
    const float* ftw  = (const float*)d_in[8];
    const float* ftb  = (const float*)d_in[9];
    float* out = (float*)d_out;

    u16*   P1b     = (u16*)d_ws;
    u16*   P2b     = P1b + (size_t)N_NODES * HID;
    u16*   xb      = P2b + (size_t)N_NODES * HID;
    u16*   Whtb    = xb + (size_t)N_NODES * IN_DIM;
    float* expS    = (float*)(Whtb + (size_t)EDGE_DIM * HID);
    float* partials = expS + (size_t)E_EDGES;
    float* sumExp  = partials + EB;

    k_init   <<<(N_NODES * IN_DIM) / 256, 256, 0, stream>>>(x, out, xb);
    k_trans  <<<(EDGE_DIM * HID) / 256, 256, 0, stream>>>(Whw, Whtb);
    k_proj   <<<N_NODES / 16, 256, 0, stream>>>(x, Wnw, Whb, Wnb, P1b, P2b);
    k_edge   <<<EB, 256, 0, stream>>>(eidx, ea, Whtb, P1b, P2b, we, expS, partials);
    k_sum    <<<1, 256, 0, stream>>>(partials, sumExp);
    k_scatter<<<2500, 256, 0, stream>>>(eidx, xb, expS, sumExp, out);
    k_final  <<<N_NODES / 16, 256, 0, stream>>>(x, ftw, ftb, out);
}

// Round 4
// 587.388 us; speedup vs baseline: 2.4301x; 1.6339x over previous
//
#include <hip/hip_runtime.h>
#include <math.h>

#define N_NODES 40000
#define E_EDGES 640000
#define IN_DIM 128
#define EDGE_DIM 64
#define HID 128
#define EB 10000   // edge blocks for k_edge (E/64)

typedef unsigned int u32;
typedef unsigned short u16;
typedef __attribute__((ext_vector_type(4))) float f32x4;
typedef __attribute__((ext_vector_type(8))) short bf16x8;

__device__ __forceinline__ float bf_lo(u32 d) { return __uint_as_float(d << 16); }
__device__ __forceinline__ float bf_hi(u32 d) { return __uint_as_float(d & 0xffff0000u); }
__device__ __forceinline__ u16 f2bf(float f) {            // RNE
    u32 u = __float_as_uint(f);
    return (u16)((u + 0x7fffu + ((u >> 16) & 1u)) >> 16);
}

// ---------------------------------------------------------------------------
// ws layout:
//   P1b  [N*HID] u16, P2b [N*HID] u16, xb [N*IN] u16, Whtb [HID*EDGE_DIM] u16
//   expS [E] f32, partials [EB] f32, sumExp [1] f32
//   counts [N] u32, off [N+1] u32, cur [N] u32
//   sdst [E] u32, sa [E] f32   (CSR: dst index + premultiplied -alpha)
// ---------------------------------------------------------------------------

__global__ __launch_bounds__(256) void k_init(const float* __restrict__ x,
                                              u16* __restrict__ xb,
                                              u32* __restrict__ counts) {
    int i = blockIdx.x * 256 + threadIdx.x;   // covers N*IN_DIM exactly
    xb[i] = f2bf(x[i]);
    if (i < N_NODES) counts[i] = 0;
}

__global__ __launch_bounds__(256) void k_trans(const float* __restrict__ Wh,
                                               u16* __restrict__ Whtb) {
    int i = blockIdx.x * 256 + threadIdx.x;   // 8192 exactly
    int h = i >> 6;
    int k = i & 63;
    Whtb[i] = f2bf(Wh[k * HID + h]);
}

__global__ __launch_bounds__(256) void k_proj(const float* __restrict__ x,
                                              const float* __restrict__ Wn,
                                              const float* __restrict__ Whb,
                                              const float* __restrict__ Wnb,
                                              u16* __restrict__ P1b,
                                              u16* __restrict__ P2b) {
    __shared__ float xs[16][IN_DIM];
    const int rowBase = blockIdx.x * 16;

    const float4* xsrc = (const float4*)(x + (size_t)rowBase * IN_DIM);
    float4* xd = (float4*)&xs[0][0];
    for (int i = threadIdx.x; i < 16 * IN_DIM / 4; i += 256) xd[i] = xsrc[i];
    __syncthreads();

    const int h  = threadIdx.x & 127;
    const int rg = threadIdx.x >> 7;

    float acc1[8], acc2[8];
#pragma unroll
    for (int r = 0; r < 8; ++r) { acc1[r] = 0.f; acc2[r] = 0.f; }

    for (int k = 0; k < IN_DIM; ++k) {
        float wa = Wn[k * HID + h];
        float wb = Wn[(IN_DIM + k) * HID + h];
#pragma unroll
        for (int r = 0; r < 8; ++r) {
            float xv = xs[rg * 8 + r][k];
            acc1[r] += xv * wa;
            acc2[r] += xv * wb;
        }
    }
    const float bias = Whb[h] + Wnb[h];
#pragma unroll
    for (int r = 0; r < 8; ++r) {
        int row = rowBase + rg * 8 + r;
        P1b[(size_t)row * HID + h] = f2bf(acc1[r] + bias);
        P2b[(size_t)row * HID + h] = f2bf(acc2[r]);
    }
}

__global__ __launch_bounds__(256) void k_hist(const int* __restrict__ eidx,
                                              u32* __restrict__ counts) {
    int e = blockIdx.x * 256 + threadIdx.x;   // E exactly
    atomicAdd(&counts[eidx[e]], 1u);
}

// single-block exclusive scan of counts[0..N) -> off[0..N], cur copy
__global__ __launch_bounds__(1024) void k_scan(const u32* __restrict__ counts,
                                               u32* __restrict__ off,
                                               u32* __restrict__ cur) {
    __shared__ u32 sums[1024];
    const int t = threadIdx.x;
    const int CH = 40;                         // 1024*40 >= N
    u32 local[CH];
    u32 s = 0;
    const int base = t * CH;
#pragma unroll
    for (int i = 0; i < CH; ++i) {
        int idx = base + i;
        u32 c = (idx < N_NODES) ? counts[idx] : 0u;
        local[i] = s;
        s += c;
    }
    sums[t] = s;
    __syncthreads();
    // Hillis-Steele inclusive scan over 1024 partials
    for (int o = 1; o < 1024; o <<= 1) {
        u32 v = (t >= o) ? sums[t - o] : 0u;
        __syncthreads();
        sums[t] += v;
        __syncthreads();
    }
    const u32 pre = sums[t] - s;               // exclusive prefix of this chunk
#pragma unroll
    for (int i = 0; i < CH; ++i) {
        int idx = base + i;
        if (idx < N_NODES) {
            u32 v = pre + local[i];
            off[idx] = v;
            cur[idx] = v;
        }
    }
    if (t == 1023) off[N_NODES] = sums[1023];
}

// MFMA edge kernel (unchanged from R3)
__global__ __launch_bounds__(256) void k_edge(const int* __restrict__ eidx,
                                              const float* __restrict__ ea,
                                              const u16* __restrict__ Whtb,
                                              const u16* __restrict__ P1b,
                                              const u16* __restrict__ P2b,
                                              const float* __restrict__ we,
                                              float* __restrict__ expS,
                                              float* __restrict__ partials) {
    __shared__ float Ps[64][132];
    __shared__ float wsumLds[4];
    const int e0 = blockIdx.x * 64;
    const int t = threadIdx.x;

    {
        const int m = t >> 2, c4 = t & 3;
        int src = eidx[e0 + m];
        int dst = eidx[E_EDGES + e0 + m];
        const uint4* p1 = (const uint4*)(P1b + (size_t)src * HID + c4 * 32);
        const uint4* p2 = (const uint4*)(P2b + (size_t)dst * HID + c4 * 32);
#pragma unroll
        for (int i = 0; i < 4; ++i) {
            uint4 ua = p1[i], ub = p2[i];
            u32 da[4] = {ua.x, ua.y, ua.z, ua.w};
            u32 db[4] = {ub.x, ub.y, ub.z, ub.w};
#pragma unroll
            for (int j = 0; j < 4; ++j) {
                Ps[m][c4 * 32 + i * 8 + 2 * j]     = bf_lo(da[j]) + bf_lo(db[j]);
                Ps[m][c4 * 32 + i * 8 + 2 * j + 1] = bf_hi(da[j]) + bf_hi(db[j]);
            }
        }
    }
    __syncthreads();

    const int w = t >> 6, lane = t & 63;
    const int mrow = lane & 15, quad = lane >> 4;
    const int mt = w;

    const float* arow = ea + (size_t)(e0 + mt * 16 + mrow) * EDGE_DIM + quad * 8;
    bf16x8 a0, a1;
#pragma unroll
    for (int ks = 0; ks < 2; ++ks) {
        float4 f0 = *(const float4*)(arow + ks * 32);
        float4 f1 = *(const float4*)(arow + ks * 32 + 4);
        bf16x8& af = ks ? a1 : a0;
        af[0] = (short)f2bf(f0.x); af[1] = (short)f2bf(f0.y);
        af[2] = (short)f2bf(f0.z); af[3] = (short)f2bf(f0.w);
        af[4] = (short)f2bf(f1.x); af[5] = (short)f2bf(f1.y);
        af[6] = (short)f2bf(f1.z); af[7] = (short)f2bf(f1.w);
    }

    float wsum[4] = {0.f, 0.f, 0.f, 0.f};
    const u16* bbase = Whtb + (size_t)mrow * EDGE_DIM + quad * 8;
#pragma unroll
    for (int nt = 0; nt < 8; ++nt) {
        const u16* bp = bbase + nt * 16 * EDGE_DIM;
        bf16x8 b0 = *(const bf16x8*)(bp);
        bf16x8 b1 = *(const bf16x8*)(bp + 32);
        f32x4 c = {0.f, 0.f, 0.f, 0.f};
        c = __builtin_amdgcn_mfma_f32_16x16x32_bf16(a0, b0, c, 0, 0, 0);
        c = __builtin_amdgcn_mfma_f32_16x16x32_bf16(a1, b1, c, 0, 0, 0);
        float wv = we[nt * 16 + mrow];
#pragma unroll
        for (int r = 0; r < 4; ++r) {
            float v = c[r] + Ps[mt * 16 + quad * 4 + r][nt * 16 + mrow];
            wsum[r] += fmaxf(v, 0.f) * wv;
        }
    }

#pragma unroll
    for (int off = 1; off < 16; off <<= 1) {
#pragma unroll
        for (int r = 0; r < 4; ++r) wsum[r] += __shfl_xor(wsum[r], off, 16);
    }
    float ex[4]; float s4 = 0.f;
#pragma unroll
    for (int r = 0; r < 4; ++r) { ex[r] = __expf(wsum[r]); s4 += ex[r]; }
    if (mrow == 0) {
#pragma unroll
        for (int r = 0; r < 4; ++r) expS[e0 + mt * 16 + quad * 4 + r] = ex[r];
    }
    s4 += __shfl_xor(s4, 16, 64);
    s4 += __shfl_xor(s4, 32, 64);
    if (lane == 0) wsumLds[w] = s4;
    __syncthreads();
    if (t == 0) partials[blockIdx.x] = wsumLds[0] + wsumLds[1] + wsumLds[2] + wsumLds[3];
}

__global__ __launch_bounds__(256) void k_sum(const float* __restrict__ partials,
                                             float* __restrict__ sumExp) {
    float s = 0.f;
    for (int i = threadIdx.x; i < EB; i += 256) s += partials[i];
#pragma unroll
    for (int off = 1; off < 64; off <<= 1) s += __shfl_xor(s, off, 64);
    __shared__ float ws4[4];
    if ((threadIdx.x & 63) == 0) ws4[threadIdx.x >> 6] = s;
    __syncthreads();
    if (threadIdx.x == 0) sumExp[0] = ws4[0] + ws4[1] + ws4[2] + ws4[3];
}

// CSR fill: slot = cur[src]++; store dst and premultiplied -alpha
__global__ __launch_bounds__(256) void k_fill(const int* __restrict__ eidx,
                                              const float* __restrict__ expS,
                                              const float* __restrict__ sumExp,
                                              u32* __restrict__ cur,
                                              u32* __restrict__ sdst,
                                              float* __restrict__ sa) {
    const float invS = 1.0f / sumExp[0];
    int e = blockIdx.x * 256 + threadIdx.x;   // E exactly
    int src = eidx[e];
    int dst = eidx[E_EDGES + e];
    u32 pos = atomicAdd(&cur[src], 1u);
    sdst[pos] = (u32)dst;
    sa[pos]   = -expS[e] * invS;
}

// one wave per node: out[n][:] = sum_{edges of n} a * xb[dst][:]
__global__ __launch_bounds__(256) void k_accum(const u32* __restrict__ off,
                                               const u32* __restrict__ sdst,
                                               const float* __restrict__ sa,
                                               const u16* __restrict__ xb,
                                               float* __restrict__ out) {
    const int lane = threadIdx.x & 63;
    const int n = blockIdx.x * 4 + (threadIdx.x >> 6);   // grid 10000 -> 40000 waves
    const u32 o0 = off[n], o1 = off[n + 1];

    float acc0 = 0.f, acc1 = 0.f;
    for (u32 base = o0; base < o1; base += 64) {
        u32 j = base + (u32)lane;
        u32 dv = 0; float av = 0.f;
        if (j < o1) { dv = sdst[j]; av = sa[j]; }
        int cnt = (int)min(64u, o1 - base);
        for (int jj = 0; jj < cnt; ++jj) {
            u32 dst = __shfl(dv, jj, 64);
            float a = __shfl(av, jj, 64);
            u32 d = ((const u32*)(xb + (size_t)dst * IN_DIM))[lane];
            acc0 = fmaf(a, bf_lo(d), acc0);
            acc1 = fmaf(a, bf_hi(d), acc1);
        }
    }
    float* op = out + (size_t)n * IN_DIM + 2 * lane;
    op[0] = acc0;
    op[1] = acc1;
}

// out[n] = y + y@ft + ftb, y = x + local(out)
__global__ __launch_bounds__(256) void k_final(const float* __restrict__ x,
                                               const float* __restrict__ ft,
                                               const float* __restrict__ ftb,
                                               float* __restrict__ out) {
    __shared__ float ys[16][IN_DIM];
    const int rowBase = blockIdx.x * 16;

    const float4* xsrc = (const float4*)(x + (size_t)rowBase * IN_DIM);
    const float4* lsrc = (const float4*)(out + (size_t)rowBase * IN_DIM);
    float4* yd = (float4*)&ys[0][0];
    for (int i = threadIdx.x; i < 16 * IN_DIM / 4; i += 256) {
        float4 a = xsrc[i];
        float4 b = lsrc[i];
        a.x += b.x; a.y += b.y; a.z += b.z; a.w += b.w;
        yd[i] = a;
    }
    __syncthreads();

    const int h  = threadIdx.x & 127;
    const int rg = threadIdx.x >> 7;

    float acc[8];
#pragma unroll
    for (int r = 0; r < 8; ++r) acc[r] = 0.f;

    for (int k = 0; k < IN_DIM; ++k) {
        float w = ft[k * IN_DIM + h];
#pragma unroll
        for (int r = 0; r < 8; ++r) acc[r] += ys[rg * 8 + r][k] * w;
    }
    const float b = ftb[h];
#pragma unroll
    for (int r = 0; r < 8; ++r) {
        int row = rowBase + rg * 8 + r;
        out[(size_t)row * IN_DIM + h] = ys[rg * 8 + r][h] + acc[r] + b;
    }
}

extern "C" void kernel_launch(void* const* d_in, const int* in_sizes, int n_in,
                              void* d_out, int out_size, void* d_ws, size_t ws_size,
                              hipStream_t stream) {
    const float* x    = (const float*)d_in[0];
    const int*   eidx = (const int*)d_in[1];
    const float* ea   = (const float*)d_in[2];
    const float* Whw  = (const float*)d_in[3];
    const float* Whb  = (const float*)d_in[4];
    const float* Wnw  = (const float*)d_in[5];
    const float* Wnb  = (const float*)d_in[6];
    const float* we   = (const float*)d_in[7];
    const float* ftw  = (const float*)d_in[8];
    const float* ftb  = (const float*)d_in[9];
    float* out = (float*)d_out;

    u16*   P1b      = (u16*)d_ws;
    u16*   P2b      = P1b + (size_t)N_NODES * HID;
    u16*   xb       = P2b + (size_t)N_NODES * HID;
    u16*   Whtb     = xb + (size_t)N_NODES * IN_DIM;
    float* expS     = (float*)(Whtb + (size_t)EDGE_DIM * HID);
    float* partials = expS + (size_t)E_EDGES;
    float* sumExp   = partials + EB;
    u32*   counts   = (u32*)(sumExp + 1);
    u32*   off      = counts + N_NODES;
    u32*   cur      = off + N_NODES + 1;
    u32*   sdst     = cur + N_NODES;
    float* sa       = (float*)(sdst + E_EDGES);

    k_init <<<(N_NODES * IN_DIM) / 256, 256, 0, stream>>>(x, xb, counts);
    k_trans<<<(EDGE_DIM * HID) / 256, 256, 0, stream>>>(Whw, Whtb);
    k_proj <<<N_NODES / 16, 256, 0, stream>>>(x, Wnw, Whb, Wnb, P1b, P2b);
    k_hist <<<E_EDGES / 256, 256, 0, stream>>>(eidx, counts);
    k_scan <<<1, 1024, 0, stream>>>(counts, off, cur);
    k_edge <<<EB, 256, 0, stream>>>(eidx, ea, Whtb, P1b, P2b, we, expS, partials);
    k_sum  <<<1, 256, 0, stream>>>(partials, sumExp);
    k_fill <<<E_EDGES / 256, 256, 0, stream>>>(eidx, expS, sumExp, cur, sdst, sa);
    k_accum<<<N_NODES / 4, 256, 0, stream>>>(off, sdst, sa, xb, out);
    k_final<<<N_NODES / 16, 256, 0, stream>>>(x, ftw, ftb, out);
}

// Round 5
// 570.292 us; speedup vs baseline: 2.5029x; 1.0300x over previous
//
#include <hip/hip_runtime.h>
#include <math.h>

#define N_NODES 40000
#define E_EDGES 640000
#define IN_DIM 128
#define EDGE_DIM 64
#define HID 128
#define EB 10000   // edge blocks for k_edge (E/64)

typedef unsigned int u32;
typedef unsigned short u16;
typedef __attribute__((ext_vector_type(4))) float f32x4;
typedef __attribute__((ext_vector_type(8))) short bf16x8;

__device__ __forceinline__ float bf_lo(u32 d) { return __uint_as_float(d << 16); }
__device__ __forceinline__ float bf_hi(u32 d) { return __uint_as_float(d & 0xffff0000u); }
__device__ __forceinline__ u16 f2bf(float f) {            // RNE
    u32 u = __float_as_uint(f);
    return (u16)((u + 0x7fffu + ((u >> 16) & 1u)) >> 16);
}
__device__ __forceinline__ u32 pack_bf(float lo, float hi) {
    return ((u32)f2bf(hi) << 16) | (u32)f2bf(lo);
}

// ---------------------------------------------------------------------------
// ws layout:
//   P1b [N*HID] u16, P2b [N*HID] u16, xb [N*IN] u16
//   Whtb [HID*EDGE_DIM] u16, WnAT [HID*IN] u16, WnBT [HID*IN] u16, fttb [IN*IN] u16
//   expS [E] f32, partials [EB] f32, sumExp [1] f32
//   counts [N] u32, off [N+1] u32, cur [N] u32, sdst [E] u32, sa [E] f32
// ---------------------------------------------------------------------------

__global__ __launch_bounds__(256) void k_init(const float* __restrict__ x,
                                              u16* __restrict__ xb,
                                              u32* __restrict__ counts) {
    int i = blockIdx.x * 256 + threadIdx.x;   // covers N*IN_DIM exactly
    xb[i] = f2bf(x[i]);
    if (i < N_NODES) counts[i] = 0;
}

// transpose+cast all weight matrices to bf16 [n][k] layouts (57344 elems)
__global__ __launch_bounds__(256) void k_trans(const float* __restrict__ Whw,
                                               const float* __restrict__ Wnw,
                                               const float* __restrict__ ftw,
                                               u16* __restrict__ Whtb,
                                               u16* __restrict__ WnAT,
                                               u16* __restrict__ WnBT,
                                               u16* __restrict__ fttb) {
    int i = blockIdx.x * 256 + threadIdx.x;
    if (i < 8192) {
        int h = i >> 6, k = i & 63;
        Whtb[i] = f2bf(Whw[k * HID + h]);
    } else if (i < 24576) {
        int j = i - 8192, h = j >> 7, k = j & 127;
        WnAT[j] = f2bf(Wnw[k * HID + h]);
    } else if (i < 40960) {
        int j = i - 24576, h = j >> 7, k = j & 127;
        WnBT[j] = f2bf(Wnw[(IN_DIM + k) * HID + h]);
    } else {
        int j = i - 40960, h = j >> 7, k = j & 127;
        fttb[j] = f2bf(ftw[k * IN_DIM + h]);
    }
}

// MFMA node projection: P1 = xb@WnA + (Whb+Wnb), P2 = xb@WnB  (bf16 out)
// block = 64 nodes, 4 waves; wave = 16-node m-tile, all 128 h.
__global__ __launch_bounds__(256) void k_proj(const u16* __restrict__ xb,
                                              const u16* __restrict__ WnAT,
                                              const u16* __restrict__ WnBT,
                                              const float* __restrict__ Whb,
                                              const float* __restrict__ Wnb,
                                              u16* __restrict__ P1b,
                                              u16* __restrict__ P2b) {
    const int t = threadIdx.x, w = t >> 6, lane = t & 63;
    const int mrow = lane & 15, quad = lane >> 4;
    const int rowBase = blockIdx.x * 64 + w * 16;

    bf16x8 a[4];
    const u16* ar = xb + (size_t)(rowBase + mrow) * IN_DIM + quad * 8;
#pragma unroll
    for (int ks = 0; ks < 4; ++ks) a[ks] = *(const bf16x8*)(ar + ks * 32);

#pragma unroll
    for (int nt = 0; nt < 8; ++nt) {
        const u16* b1p = WnAT + (size_t)(nt * 16 + mrow) * IN_DIM + quad * 8;
        const u16* b2p = WnBT + (size_t)(nt * 16 + mrow) * IN_DIM + quad * 8;
        f32x4 c1 = {0.f, 0.f, 0.f, 0.f}, c2 = {0.f, 0.f, 0.f, 0.f};
#pragma unroll
        for (int ks = 0; ks < 4; ++ks) {
            c1 = __builtin_amdgcn_mfma_f32_16x16x32_bf16(a[ks], *(const bf16x8*)(b1p + ks * 32), c1, 0, 0, 0);
            c2 = __builtin_amdgcn_mfma_f32_16x16x32_bf16(a[ks], *(const bf16x8*)(b2p + ks * 32), c2, 0, 0, 0);
        }
        const int col = nt * 16 + mrow;
        const float bias = Whb[col] + Wnb[col];
#pragma unroll
        for (int r = 0; r < 4; ++r) {
            int row = rowBase + quad * 4 + r;
            P1b[(size_t)row * HID + col] = f2bf(c1[r] + bias);
            P2b[(size_t)row * HID + col] = f2bf(c2[r]);
        }
    }
}

__global__ __launch_bounds__(256) void k_hist(const int* __restrict__ eidx,
                                              u32* __restrict__ counts) {
    int e = blockIdx.x * 256 + threadIdx.x;   // E exactly
    atomicAdd(&counts[eidx[e]], 1u);
}

__global__ __launch_bounds__(1024) void k_scan(const u32* __restrict__ counts,
                                               u32* __restrict__ off,
                                               u32* __restrict__ cur) {
    __shared__ u32 sums[1024];
    const int t = threadIdx.x;
    const int CH = 40;
    u32 local[CH];
    u32 s = 0;
    const int base = t * CH;
#pragma unroll
    for (int i = 0; i < CH; ++i) {
        int idx = base + i;
        u32 c = (idx < N_NODES) ? counts[idx] : 0u;
        local[i] = s;
        s += c;
    }
    sums[t] = s;
    __syncthreads();
    for (int o = 1; o < 1024; o <<= 1) {
        u32 v = (t >= o) ? sums[t - o] : 0u;
        __syncthreads();
        sums[t] += v;
        __syncthreads();
    }
    const u32 pre = sums[t] - s;
#pragma unroll
    for (int i = 0; i < CH; ++i) {
        int idx = base + i;
        if (idx < N_NODES) {
            u32 v = pre + local[i];
            off[idx] = v;
            cur[idx] = v;
        }
    }
    if (t == 1023) off[N_NODES] = sums[1023];
}

// MFMA edge kernel; Ps staged as packed bf16 pairs (17 KB LDS, conflict-free)
__global__ __launch_bounds__(256) void k_edge(const int* __restrict__ eidx,
                                              const float* __restrict__ ea,
                                              const u16* __restrict__ Whtb,
                                              const u16* __restrict__ P1b,
                                              const u16* __restrict__ P2b,
                                              const float* __restrict__ we,
                                              float* __restrict__ expS,
                                              float* __restrict__ partials) {
    __shared__ u32 Psp[64][68];   // row stride 68 u32: 16B-aligned rows, <=2-way banks
    __shared__ float wsumLds[4];
    const int e0 = blockIdx.x * 64;
    const int t = threadIdx.x;

    // gather node term: Psp[m][j] = packed bf16 pair of (P1[src]+P2[dst]) at h=2j,2j+1
    {
        const int m = t >> 2, c4 = t & 3;
        int src = eidx[e0 + m];
        int dst = eidx[E_EDGES + e0 + m];
        const uint4* p1 = (const uint4*)(P1b + (size_t)src * HID + c4 * 32);
        const uint4* p2 = (const uint4*)(P2b + (size_t)dst * HID + c4 * 32);
#pragma unroll
        for (int i = 0; i < 4; ++i) {
            uint4 ua = p1[i], ub = p2[i];
            u32 da[4] = {ua.x, ua.y, ua.z, ua.w};
            u32 db[4] = {ub.x, ub.y, ub.z, ub.w};
            uint4 o;
            o.x = pack_bf(bf_lo(da[0]) + bf_lo(db[0]), bf_hi(da[0]) + bf_hi(db[0]));
            o.y = pack_bf(bf_lo(da[1]) + bf_lo(db[1]), bf_hi(da[1]) + bf_hi(db[1]));
            o.z = pack_bf(bf_lo(da[2]) + bf_lo(db[2]), bf_hi(da[2]) + bf_hi(db[2]));
            o.w = pack_bf(bf_lo(da[3]) + bf_lo(db[3]), bf_hi(da[3]) + bf_hi(db[3]));
            *(uint4*)&Psp[m][c4 * 16 + i * 4] = o;
        }
    }
    __syncthreads();

    const int w = t >> 6, lane = t & 63;
    const int mrow = lane & 15, quad = lane >> 4;
    const int mt = w;

    const float* arow = ea + (size_t)(e0 + mt * 16 + mrow) * EDGE_DIM + quad * 8;
    bf16x8 a0, a1;
#pragma unroll
    for (int ks = 0; ks < 2; ++ks) {
        float4 f0 = *(const float4*)(arow + ks * 32);
        float4 f1 = *(const float4*)(arow + ks * 32 + 4);
        bf16x8& af = ks ? a1 : a0;
        af[0] = (short)f2bf(f0.x); af[1] = (short)f2bf(f0.y);
        af[2] = (short)f2bf(f0.z); af[3] = (short)f2bf(f0.w);
        af[4] = (short)f2bf(f1.x); af[5] = (short)f2bf(f1.y);
        af[6] = (short)f2bf(f1.z); af[7] = (short)f2bf(f1.w);
    }

    float wsum[4] = {0.f, 0.f, 0.f, 0.f};
    const u16* bbase = Whtb + (size_t)mrow * EDGE_DIM + quad * 8;
#pragma unroll
    for (int nt = 0; nt < 8; ++nt) {
        const u16* bp = bbase + nt * 16 * EDGE_DIM;
        bf16x8 b0 = *(const bf16x8*)(bp);
        bf16x8 b1 = *(const bf16x8*)(bp + 32);
        f32x4 c = {0.f, 0.f, 0.f, 0.f};
        c = __builtin_amdgcn_mfma_f32_16x16x32_bf16(a0, b0, c, 0, 0, 0);
        c = __builtin_amdgcn_mfma_f32_16x16x32_bf16(a1, b1, c, 0, 0, 0);
        float wv = we[nt * 16 + mrow];
#pragma unroll
        for (int r = 0; r < 4; ++r) {
            u32 u = Psp[mt * 16 + quad * 4 + r][nt * 8 + (mrow >> 1)];
            float p = (mrow & 1) ? bf_hi(u) : bf_lo(u);
            wsum[r] += fmaxf(c[r] + p, 0.f) * wv;
        }
    }

#pragma unroll
    for (int off = 1; off < 16; off <<= 1) {
#pragma unroll
        for (int r = 0; r < 4; ++r) wsum[r] += __shfl_xor(wsum[r], off, 16);
    }
    float ex[4]; float s4 = 0.f;
#pragma unroll
    for (int r = 0; r < 4; ++r) { ex[r] = __expf(wsum[r]); s4 += ex[r]; }
    if (mrow == 0) {
#pragma unroll
        for (int r = 0; r < 4; ++r) expS[e0 + mt * 16 + quad * 4 + r] = ex[r];
    }
    s4 += __shfl_xor(s4, 16, 64);
    s4 += __shfl_xor(s4, 32, 64);
    if (lane == 0) wsumLds[w] = s4;
    __syncthreads();
    if (t == 0) partials[blockIdx.x] = wsumLds[0] + wsumLds[1] + wsumLds[2] + wsumLds[3];
}

__global__ __launch_bounds__(256) void k_sum(const float* __restrict__ partials,
                                             float* __restrict__ sumExp) {
    float s = 0.f;
    for (int i = threadIdx.x; i < EB; i += 256) s += partials[i];
#pragma unroll
    for (int off = 1; off < 64; off <<= 1) s += __shfl_xor(s, off, 64);
    __shared__ float ws4[4];
    if ((threadIdx.x & 63) == 0) ws4[threadIdx.x >> 6] = s;
    __syncthreads();
    if (threadIdx.x == 0) sumExp[0] = ws4[0] + ws4[1] + ws4[2] + ws4[3];
}

__global__ __launch_bounds__(256) void k_fill(const int* __restrict__ eidx,
                                              const float* __restrict__ expS,
                                              const float* __restrict__ sumExp,
                                              u32* __restrict__ cur,
                                              u32* __restrict__ sdst,
                                              float* __restrict__ sa) {
    const float invS = 1.0f / sumExp[0];
    int e = blockIdx.x * 256 + threadIdx.x;   // E exactly
    int src = eidx[e];
    int dst = eidx[E_EDGES + e];
    u32 pos = atomicAdd(&cur[src], 1u);
    sdst[pos] = (u32)dst;
    sa[pos]   = -expS[e] * invS;
}

// one wave per node: out[n][:] = sum_{edges of n} a * xb[dst][:]
__global__ __launch_bounds__(256) void k_accum(const u32* __restrict__ off,
                                               const u32* __restrict__ sdst,
                                               const float* __restrict__ sa,
                                               const u16* __restrict__ xb,
                                               float* __restrict__ out) {
    const int lane = threadIdx.x & 63;
    const int n = blockIdx.x * 4 + (threadIdx.x >> 6);
    const u32 o0 = off[n], o1 = off[n + 1];

    float acc0 = 0.f, acc1 = 0.f;
    for (u32 base = o0; base < o1; base += 64) {
        u32 j = base + (u32)lane;
        u32 dv = 0; float av = 0.f;
        if (j < o1) { dv = sdst[j]; av = sa[j]; }
        int cnt = (int)min(64u, o1 - base);
        for (int jj = 0; jj < cnt; ++jj) {
            u32 dst = __shfl(dv, jj, 64);
            float a = __shfl(av, jj, 64);
            u32 d = ((const u32*)(xb + (size_t)dst * IN_DIM))[lane];
            acc0 = fmaf(a, bf_lo(d), acc0);
            acc1 = fmaf(a, bf_hi(d), acc1);
        }
    }
    float* op = out + (size_t)n * IN_DIM + 2 * lane;
    op[0] = acc0;
    op[1] = acc1;
}

// MFMA finisher: out = y + y@ft + ftb, y = x + local(out). In-place per row-block.
__global__ __launch_bounds__(256) void k_final(const float* __restrict__ x,
                                               const u16* __restrict__ fttb,
                                               const float* __restrict__ ftb,
                                               float* __restrict__ out) {
    __shared__ u32 ybp[64][68];   // packed bf16 y
    const int t = threadIdx.x;
    const int rb = blockIdx.x * 64;

    {   // stage y = x + local as packed bf16
        const int rr = t >> 2, seg = t & 3;
        const float4* xp = (const float4*)(x + (size_t)(rb + rr) * IN_DIM + seg * 32);
        const float4* lp = (const float4*)(out + (size_t)(rb + rr) * IN_DIM + seg * 32);
#pragma unroll
        for (int i = 0; i < 4; ++i) {
            float4 xa = xp[2 * i], xc = xp[2 * i + 1];
            float4 la = lp[2 * i], lc = lp[2 * i + 1];
            uint4 o;
            o.x = pack_bf(xa.x + la.x, xa.y + la.y);
            o.y = pack_bf(xa.z + la.z, xa.w + la.w);
            o.z = pack_bf(xc.x + lc.x, xc.y + lc.y);
            o.w = pack_bf(xc.z + lc.z, xc.w + lc.w);
            *(uint4*)&ybp[rr][seg * 16 + i * 4] = o;
        }
    }
    __syncthreads();

    const int w = t >> 6, lane = t & 63;
    const int mrow = lane & 15, quad = lane >> 4;
    const int rowBase = rb + w * 16;

    bf16x8 a[4];
#pragma unroll
    for (int ks = 0; ks < 4; ++ks)
        a[ks] = *(const bf16x8*)&ybp[w * 16 + mrow][ks * 16 + quad * 4];

#pragma unroll
    for (int nt = 0; nt < 8; ++nt) {
        const u16* bp = fttb + (size_t)(nt * 16 + mrow) * IN_DIM + quad * 8;
        f32x4 c = {0.f, 0.f, 0.f, 0.f};
#pragma unroll
        for (int ks = 0; ks < 4; ++ks)
            c = __builtin_amdgcn_mfma_f32_16x16x32_bf16(a[ks], *(const bf16x8*)(bp + ks * 32), c, 0, 0, 0);
        const int col = nt * 16 + mrow;
        const float fb = ftb[col];
#pragma unroll
        for (int r = 0; r < 4; ++r) {
            int row = rowBase + quad * 4 + r;
            size_t idx = (size_t)row * IN_DIM + col;
            float y = x[idx] + out[idx];      // exact fp32 y term
            out[idx] = y + c[r] + fb;
        }
    }
}

extern "C" void kernel_launch(void* const* d_in, const int* in_sizes, int n_in,
                              void* d_out, int out_size, void* d_ws, size_t ws_size,
                              hipStream_t stream) {
    const float* x    = (const float*)d_in[0];
    const int*   eidx = (const int*)d_in[1];
    const float* ea   = (const float*)d_in[2];
    const float* Whw  = (const float*)d_in[3];
    const float* Whb  = (const float*)d_in[4];
    const float* Wnw  = (const float*)d_in[5];
    const float* Wnb  = (const float*)d_in[6];
    const float* we   = (const float*)d_in[7];
    const float* ftw  = (const float*)d_in[8];
    const float* ftb  = (const float*)d_in[9];
    float* out = (float*)d_out;

    u16*   P1b      = (u16*)d_ws;
    u16*   P2b      = P1b + (size_t)N_NODES * HID;
    u16*   xb       = P2b + (size_t)N_NODES * HID;
    u16*   Whtb     = xb + (size_t)N_NODES * IN_DIM;
    u16*   WnAT     = Whtb + (size_t)EDGE_DIM * HID;
    u16*   WnBT     = WnAT + (size_t)HID * IN_DIM;
    u16*   fttb     = WnBT + (size_t)HID * IN_DIM;
    float* expS     = (float*)(fttb + (size_t)IN_DIM * IN_DIM);
    float* partials = expS + (size_t)E_EDGES;
    float* sumExp   = partials + EB;
    u32*   counts   = (u32*)(sumExp + 1);
    u32*   off      = counts + N_NODES;
    u32*   cur      = off + N_NODES + 1;
    u32*   sdst     = cur + N_NODES;
    float* sa       = (float*)(sdst + E_EDGES);

    k_init <<<(N_NODES * IN_DIM) / 256, 256, 0, stream>>>(x, xb, counts);
    k_trans<<<224, 256, 0, stream>>>(Whw, Wnw, ftw, Whtb, WnAT, WnBT, fttb);
    k_proj <<<N_NODES / 64, 256, 0, stream>>>(xb, WnAT, WnBT, Whb, Wnb, P1b, P2b);
    k_hist <<<E_EDGES / 256, 256, 0, stream>>>(eidx, counts);
    k_scan <<<1, 1024, 0, stream>>>(counts, off, cur);
    k_edge <<<EB, 256, 0, stream>>>(eidx, ea, Whtb, P1b, P2b, we, expS, partials);
    k_sum  <<<1, 256, 0, stream>>>(partials, sumExp);
    k_fill <<<E_EDGES / 256, 256, 0, stream>>>(eidx, expS, sumExp, cur, sdst, sa);
    k_accum<<<N_NODES / 4, 256, 0, stream>>>(off, sdst, sa, xb, out);
    k_final<<<N_NODES / 64, 256, 0, stream>>>(x, fttb, ftb, out);
}

// Round 6
// 565.392 us; speedup vs baseline: 2.5246x; 1.0087x over previous
//
#include <hip/hip_runtime.h>
#include <math.h>

#define N_NODES 40000
#define E_EDGES 640000
#define IN_DIM 128
#define EDGE_DIM 64
#define HID 128
#define EB 10000   // edge blocks for k_edge (E/64)
#define NPART (EB * 4)

typedef unsigned int u32;
typedef unsigned short u16;
typedef __attribute__((ext_vector_type(4))) float f32x4;
typedef __attribute__((ext_vector_type(8))) short bf16x8;

__device__ __forceinline__ float bf_lo(u32 d) { return __uint_as_float(d << 16); }
__device__ __forceinline__ float bf_hi(u32 d) { return __uint_as_float(d & 0xffff0000u); }
__device__ __forceinline__ u16 f2bf(float f) {            // RNE
    u32 u = __float_as_uint(f);
    return (u16)((u + 0x7fffu + ((u >> 16) & 1u)) >> 16);
}
__device__ __forceinline__ u32 pack_bf(float lo, float hi) {
    return ((u32)f2bf(hi) << 16) | (u32)f2bf(lo);
}

// ---------------------------------------------------------------------------
// ws layout (8-B aligned block first):
//   sde  [E] uint2 : CSR payload (dst, bits(-exp(score)))
//   P1b [N*HID] u16, P2b [N*HID] u16, xb [N*IN] u16
//   Whtb [HID*EDGE_DIM] u16, WnAT [HID*IN] u16, WnBT [HID*IN] u16, fttb [IN*IN] u16
//   partials [NPART] f32, sumExp [1] f32
//   counts [N] u32, off [N+1] u32, cur [N] u32
// ---------------------------------------------------------------------------

__global__ __launch_bounds__(256) void k_init(const float* __restrict__ x,
                                              u16* __restrict__ xb,
                                              u32* __restrict__ counts) {
    int i = blockIdx.x * 256 + threadIdx.x;   // covers N*IN_DIM exactly
    xb[i] = f2bf(x[i]);
    if (i < N_NODES) counts[i] = 0;
}

// transpose+cast all weight matrices to bf16 [n][k] layouts (57344 elems)
__global__ __launch_bounds__(256) void k_trans(const float* __restrict__ Whw,
                                               const float* __restrict__ Wnw,
                                               const float* __restrict__ ftw,
                                               u16* __restrict__ Whtb,
                                               u16* __restrict__ WnAT,
                                               u16* __restrict__ WnBT,
                                               u16* __restrict__ fttb) {
    int i = blockIdx.x * 256 + threadIdx.x;
    if (i < 8192) {
        int h = i >> 6, k = i & 63;
        Whtb[i] = f2bf(Whw[k * HID + h]);
    } else if (i < 24576) {
        int j = i - 8192, h = j >> 7, k = j & 127;
        WnAT[j] = f2bf(Wnw[k * HID + h]);
    } else if (i < 40960) {
        int j = i - 24576, h = j >> 7, k = j & 127;
        WnBT[j] = f2bf(Wnw[(IN_DIM + k) * HID + h]);
    } else {
        int j = i - 40960, h = j >> 7, k = j & 127;
        fttb[j] = f2bf(ftw[k * IN_DIM + h]);
    }
}

// MFMA node projection: P1 = xb@WnA + (Whb+Wnb), P2 = xb@WnB  (bf16 out)
__global__ __launch_bounds__(256) void k_proj(const u16* __restrict__ xb,
                                              const u16* __restrict__ WnAT,
                                              const u16* __restrict__ WnBT,
                                              const float* __restrict__ Whb,
                                              const float* __restrict__ Wnb,
                                              u16* __restrict__ P1b,
                                              u16* __restrict__ P2b) {
    const int t = threadIdx.x, w = t >> 6, lane = t & 63;
    const int mrow = lane & 15, quad = lane >> 4;
    const int rowBase = blockIdx.x * 64 + w * 16;

    bf16x8 a[4];
    const u16* ar = xb + (size_t)(rowBase + mrow) * IN_DIM + quad * 8;
#pragma unroll
    for (int ks = 0; ks < 4; ++ks) a[ks] = *(const bf16x8*)(ar + ks * 32);

#pragma unroll
    for (int nt = 0; nt < 8; ++nt) {
        const u16* b1p = WnAT + (size_t)(nt * 16 + mrow) * IN_DIM + quad * 8;
        const u16* b2p = WnBT + (size_t)(nt * 16 + mrow) * IN_DIM + quad * 8;
        f32x4 c1 = {0.f, 0.f, 0.f, 0.f}, c2 = {0.f, 0.f, 0.f, 0.f};
#pragma unroll
        for (int ks = 0; ks < 4; ++ks) {
            c1 = __builtin_amdgcn_mfma_f32_16x16x32_bf16(a[ks], *(const bf16x8*)(b1p + ks * 32), c1, 0, 0, 0);
            c2 = __builtin_amdgcn_mfma_f32_16x16x32_bf16(a[ks], *(const bf16x8*)(b2p + ks * 32), c2, 0, 0, 0);
        }
        const int col = nt * 16 + mrow;
        const float bias = Whb[col] + Wnb[col];
#pragma unroll
        for (int r = 0; r < 4; ++r) {
            int row = rowBase + quad * 4 + r;
            P1b[(size_t)row * HID + col] = f2bf(c1[r] + bias);
            P2b[(size_t)row * HID + col] = f2bf(c2[r]);
        }
    }
}

__global__ __launch_bounds__(256) void k_hist(const int* __restrict__ eidx,
                                              u32* __restrict__ counts) {
    int e = blockIdx.x * 256 + threadIdx.x;   // E exactly
    atomicAdd(&counts[eidx[e]], 1u);
}

__global__ __launch_bounds__(1024) void k_scan(const u32* __restrict__ counts,
                                               u32* __restrict__ off,
                                               u32* __restrict__ cur) {
    __shared__ u32 sums[1024];
    const int t = threadIdx.x;
    const int CH = 40;
    u32 local[CH];
    u32 s = 0;
    const int base = t * CH;
#pragma unroll
    for (int i = 0; i < CH; ++i) {
        int idx = base + i;
        u32 c = (idx < N_NODES) ? counts[idx] : 0u;
        local[i] = s;
        s += c;
    }
    sums[t] = s;
    __syncthreads();
    for (int o = 1; o < 1024; o <<= 1) {
        u32 v = (t >= o) ? sums[t - o] : 0u;
        __syncthreads();
        sums[t] += v;
        __syncthreads();
    }
    const u32 pre = sums[t] - s;
#pragma unroll
    for (int i = 0; i < CH; ++i) {
        int idx = base + i;
        if (idx < N_NODES) {
            u32 v = pre + local[i];
            off[idx] = v;
            cur[idx] = v;
        }
    }
    if (t == 1023) off[N_NODES] = sums[1023];
}

// Wave-autonomous MFMA edge kernel + fused CSR fill. No __syncthreads.
// Each wave owns 16 edges: gathers P-rows into its private LDS slice,
// computes scores via MFMA, claims CSR slots, stores (dst, -exp).
__global__ __launch_bounds__(256) void k_edge(const int* __restrict__ eidx,
                                              const float* __restrict__ ea,
                                              const u16* __restrict__ Whtb,
                                              const u16* __restrict__ P1b,
                                              const u16* __restrict__ P2b,
                                              const float* __restrict__ we,
                                              u32* __restrict__ cur,
                                              uint2* __restrict__ sde,
                                              float* __restrict__ partials) {
    __shared__ u32 Psp[4][16][68];   // per-wave slices; stride 68 breaks pow2 banks
    const int t = threadIdx.x, w = t >> 6, lane = t & 63;
    const int e0 = blockIdx.x * 64 + w * 16;
    const int mrow = lane & 15, quad = lane >> 4;

    // --- issue ALL global loads up-front (gather + A-row) ---
    const int m = lane >> 2, c4 = lane & 3;   // lane -> edge m, quarter c4
    const int srcm = eidx[e0 + m];
    const int dstm = eidx[E_EDGES + e0 + m];
    const uint4* p1 = (const uint4*)(P1b + (size_t)srcm * HID + c4 * 32);
    const uint4* p2 = (const uint4*)(P2b + (size_t)dstm * HID + c4 * 32);
    uint4 pa[4], pb[4];
#pragma unroll
    for (int i = 0; i < 4; ++i) { pa[i] = p1[i]; pb[i] = p2[i]; }

    const float* arow = ea + (size_t)(e0 + mrow) * EDGE_DIM + quad * 8;
    float4 f0 = *(const float4*)(arow);
    float4 f1 = *(const float4*)(arow + 4);
    float4 f2 = *(const float4*)(arow + 32);
    float4 f3 = *(const float4*)(arow + 36);

    // --- pack node term into this wave's LDS slice ---
#pragma unroll
    for (int i = 0; i < 4; ++i) {
        u32 da[4] = {pa[i].x, pa[i].y, pa[i].z, pa[i].w};
        u32 db[4] = {pb[i].x, pb[i].y, pb[i].z, pb[i].w};
        uint4 o;
        o.x = pack_bf(bf_lo(da[0]) + bf_lo(db[0]), bf_hi(da[0]) + bf_hi(db[0]));
        o.y = pack_bf(bf_lo(da[1]) + bf_lo(db[1]), bf_hi(da[1]) + bf_hi(db[1]));
        o.z = pack_bf(bf_lo(da[2]) + bf_lo(db[2]), bf_hi(da[2]) + bf_hi(db[2]));
        o.w = pack_bf(bf_lo(da[3]) + bf_lo(db[3]), bf_hi(da[3]) + bf_hi(db[3]));
        *(uint4*)&Psp[w][m][c4 * 16 + i * 4] = o;
    }

    // --- A fragments from f0..f3 ---
    bf16x8 a0, a1;
    a0[0] = (short)f2bf(f0.x); a0[1] = (short)f2bf(f0.y);
    a0[2] = (short)f2bf(f0.z); a0[3] = (short)f2bf(f0.w);
    a0[4] = (short)f2bf(f1.x); a0[5] = (short)f2bf(f1.y);
    a0[6] = (short)f2bf(f1.z); a0[7] = (short)f2bf(f1.w);
    a1[0] = (short)f2bf(f2.x); a1[1] = (short)f2bf(f2.y);
    a1[2] = (short)f2bf(f2.z); a1[3] = (short)f2bf(f2.w);
    a1[4] = (short)f2bf(f3.x); a1[5] = (short)f2bf(f3.y);
    a1[6] = (short)f2bf(f3.z); a1[7] = (short)f2bf(f3.w);

    // --- MFMA over 8 n-tiles; fuse +Psum, relu, *we (wave-local LDS, no barrier) ---
    float wsum[4] = {0.f, 0.f, 0.f, 0.f};
    const u16* bbase = Whtb + (size_t)mrow * EDGE_DIM + quad * 8;
#pragma unroll
    for (int nt = 0; nt < 8; ++nt) {
        const u16* bp = bbase + nt * 16 * EDGE_DIM;
        bf16x8 b0 = *(const bf16x8*)(bp);
        bf16x8 b1 = *(const bf16x8*)(bp + 32);
        f32x4 c = {0.f, 0.f, 0.f, 0.f};
        c = __builtin_amdgcn_mfma_f32_16x16x32_bf16(a0, b0, c, 0, 0, 0);
        c = __builtin_amdgcn_mfma_f32_16x16x32_bf16(a1, b1, c, 0, 0, 0);
        float wv = we[nt * 16 + mrow];
#pragma unroll
        for (int r = 0; r < 4; ++r) {
            u32 u = Psp[w][quad * 4 + r][nt * 8 + (mrow >> 1)];
            float p = (mrow & 1) ? bf_hi(u) : bf_lo(u);
            wsum[r] += fmaxf(c[r] + p, 0.f) * wv;
        }
    }

    // --- reduce across the 16 lanes of each quad group ---
#pragma unroll
    for (int off = 1; off < 16; off <<= 1) {
#pragma unroll
        for (int r = 0; r < 4; ++r) wsum[r] += __shfl_xor(wsum[r], off, 16);
    }
    float ex[4]; float s4 = 0.f;
#pragma unroll
    for (int r = 0; r < 4; ++r) { ex[r] = __expf(wsum[r]); s4 += ex[r]; }

    // --- fused CSR fill: store (dst, -exp) unnormalized ---
    if (mrow == 0) {
#pragma unroll
        for (int r = 0; r < 4; ++r) {
            int e = e0 + quad * 4 + r;
            int s = eidx[e];
            int d = eidx[E_EDGES + e];
            u32 pos = atomicAdd(&cur[s], 1u);
            sde[pos] = make_uint2((u32)d, __float_as_uint(-ex[r]));
        }
    }

    // --- per-wave partial (no atomics, no barrier) ---
    s4 += __shfl_xor(s4, 16, 64);
    s4 += __shfl_xor(s4, 32, 64);
    if (lane == 0) partials[blockIdx.x * 4 + w] = s4;
}

__global__ __launch_bounds__(256) void k_sum(const float* __restrict__ partials,
                                             float* __restrict__ sumExp) {
    float s = 0.f;
    for (int i = threadIdx.x; i < NPART; i += 256) s += partials[i];
#pragma unroll
    for (int off = 1; off < 64; off <<= 1) s += __shfl_xor(s, off, 64);
    __shared__ float ws4[4];
    if ((threadIdx.x & 63) == 0) ws4[threadIdx.x >> 6] = s;
    __syncthreads();
    if (threadIdx.x == 0) sumExp[0] = ws4[0] + ws4[1] + ws4[2] + ws4[3];
}

// one wave per node: out[n][:] = invS * sum_{edges of n} (-exp_e) * xb[dst][:]
__global__ __launch_bounds__(256) void k_accum(const u32* __restrict__ off,
                                               const uint2* __restrict__ sde,
                                               const float* __restrict__ sumExp,
                                               const u16* __restrict__ xb,
                                               float* __restrict__ out) {
    const float invS = 1.0f / sumExp[0];
    const int lane = threadIdx.x & 63;
    const int n = blockIdx.x * 4 + (threadIdx.x >> 6);
    const u32 o0 = off[n], o1 = off[n + 1];

    float acc0 = 0.f, acc1 = 0.f;
    for (u32 base = o0; base < o1; base += 64) {
        u32 j = base + (u32)lane;
        uint2 dv = make_uint2(0u, 0u);
        if (j < o1) dv = sde[j];
        int cnt = (int)min(64u, o1 - base);
        int jj = 0;
        for (; jj + 4 <= cnt; jj += 4) {
            u32 d0 = __shfl(dv.x, jj, 64),     d1 = __shfl(dv.x, jj + 1, 64);
            u32 d2 = __shfl(dv.x, jj + 2, 64), d3 = __shfl(dv.x, jj + 3, 64);
            float a0 = __uint_as_float(__shfl(dv.y, jj, 64));
            float a1 = __uint_as_float(__shfl(dv.y, jj + 1, 64));
            float a2 = __uint_as_float(__shfl(dv.y, jj + 2, 64));
            float a3 = __uint_as_float(__shfl(dv.y, jj + 3, 64));
            u32 q0 = ((const u32*)(xb + (size_t)d0 * IN_DIM))[lane];
            u32 q1 = ((const u32*)(xb + (size_t)d1 * IN_DIM))[lane];
            u32 q2 = ((const u32*)(xb + (size_t)d2 * IN_DIM))[lane];
            u32 q3 = ((const u32*)(xb + (size_t)d3 * IN_DIM))[lane];
            acc0 = fmaf(a0, bf_lo(q0), acc0); acc1 = fmaf(a0, bf_hi(q0), acc1);
            acc0 = fmaf(a1, bf_lo(q1), acc0); acc1 = fmaf(a1, bf_hi(q1), acc1);
            acc0 = fmaf(a2, bf_lo(q2), acc0); acc1 = fmaf(a2, bf_hi(q2), acc1);
            acc0 = fmaf(a3, bf_lo(q3), acc0); acc1 = fmaf(a3, bf_hi(q3), acc1);
        }
        for (; jj < cnt; ++jj) {
            u32 dst = __shfl(dv.x, jj, 64);
            float a = __uint_as_float(__shfl(dv.y, jj, 64));
            u32 q = ((const u32*)(xb + (size_t)dst * IN_DIM))[lane];
            acc0 = fmaf(a, bf_lo(q), acc0);
            acc1 = fmaf(a, bf_hi(q), acc1);
        }
    }
    float* op = out + (size_t)n * IN_DIM + 2 * lane;
    op[0] = acc0 * invS;
    op[1] = acc1 * invS;
}

// MFMA finisher: out = y + y@ft + ftb, y = x + local(out). In-place per row-block.
__global__ __launch_bounds__(256) void k_final(const float* __restrict__ x,
                                               const u16* __restrict__ fttb,
                                               const float* __restrict__ ftb,
                                               float* __restrict__ out) {
    __shared__ u32 ybp[64][68];   // packed bf16 y
    const int t = threadIdx.x;
    const int rb = blockIdx.x * 64;

    {   // stage y = x + local as packed bf16
        const int rr = t >> 2, seg = t & 3;
        const float4* xp = (const float4*)(x + (size_t)(rb + rr) * IN_DIM + seg * 32);
        const float4* lp = (const float4*)(out + (size_t)(rb + rr) * IN_DIM + seg * 32);
#pragma unroll
        for (int i = 0; i < 4; ++i) {
            float4 xa = xp[2 * i], xc = xp[2 * i + 1];
            float4 la = lp[2 * i], lc = lp[2 * i + 1];
            uint4 o;
            o.x = pack_bf(xa.x + la.x, xa.y + la.y);
            o.y = pack_bf(xa.z + la.z, xa.w + la.w);
            o.z = pack_bf(xc.x + lc.x, xc.y + lc.y);
            o.w = pack_bf(xc.z + lc.z, xc.w + lc.w);
            *(uint4*)&ybp[rr][seg * 16 + i * 4] = o;
        }
    }
    __syncthreads();

    const int w = t >> 6, lane = t & 63;
    const int mrow = lane & 15, quad = lane >> 4;
    const int rowBase = rb + w * 16;

    bf16x8 a[4];
#pragma unroll
    for (int ks = 0; ks < 4; ++ks)
        a[ks] = *(const bf16x8*)&ybp[w * 16 + mrow][ks * 16 + quad * 4];

#pragma unroll
    for (int nt = 0; nt < 8; ++nt) {
        const u16* bp = fttb + (size_t)(nt * 16 + mrow) * IN_DIM + quad * 8;
        f32x4 c = {0.f, 0.f, 0.f, 0.f};
#pragma unroll
        for (int ks = 0; ks < 4; ++ks)
            c = __builtin_amdgcn_mfma_f32_16x16x32_bf16(a[ks], *(const bf16x8*)(bp + ks * 32), c, 0, 0, 0);
        const int col = nt * 16 + mrow;
        const float fb = ftb[col];
#pragma unroll
        for (int r = 0; r < 4; ++r) {
            int row = rowBase + quad * 4 + r;
            size_t idx = (size_t)row * IN_DIM + col;
            float y = x[idx] + out[idx];      // exact fp32 y term
            out[idx] = y + c[r] + fb;
        }
    }
}

extern "C" void kernel_launch(void* const* d_in, const int* in_sizes, int n_in,
                              void* d_out, int out_size, void* d_ws, size_t ws_size,
                              hipStream_t stream) {
    const float* x    = (const float*)d_in[0];
    const int*   eidx = (const int*)d_in[1];
    const float* ea   = (const float*)d_in[2];
    const float* Whw  = (const float*)d_in[3];
    const float* Whb  = (const float*)d_in[4];
    const float* Wnw  = (const float*)d_in[5];
    const float* Wnb  = (const float*)d_in[6];
    const float* we   = (const float*)d_in[7];
    const float* ftw  = (const float*)d_in[8];
    const float* ftb  = (const float*)d_in[9];
    float* out = (float*)d_out;

    uint2* sde      = (uint2*)d_ws;                       // 8-B aligned first
    u16*   P1b      = (u16*)(sde + (size_t)E_EDGES);
    u16*   P2b      = P1b + (size_t)N_NODES * HID;
    u16*   xb       = P2b + (size_t)N_NODES * HID;
    u16*   Whtb     = xb + (size_t)N_NODES * IN_DIM;
    u16*   WnAT     = Whtb + (size_t)EDGE_DIM * HID;
    u16*   WnBT     = WnAT + (size_t)HID * IN_DIM;
    u16*   fttb     = WnBT + (size_t)HID * IN_DIM;
    float* partials = (float*)(fttb + (size_t)IN_DIM * IN_DIM);
    float* sumExp   = partials + NPART;
    u32*   counts   = (u32*)(sumExp + 1);
    u32*   off      = counts + N_NODES;
    u32*   cur      = off + N_NODES + 1;

    k_init <<<(N_NODES * IN_DIM) / 256, 256, 0, stream>>>(x, xb, counts);
    k_trans<<<224, 256, 0, stream>>>(Whw, Wnw, ftw, Whtb, WnAT, WnBT, fttb);
    k_proj <<<N_NODES / 64, 256, 0, stream>>>(xb, WnAT, WnBT, Whb, Wnb, P1b, P2b);
    k_hist <<<E_EDGES / 256, 256, 0, stream>>>(eidx, counts);
    k_scan <<<1, 1024, 0, stream>>>(counts, off, cur);
    k_edge <<<EB, 256, 0, stream>>>(eidx, ea, Whtb, P1b, P2b, we, cur, sde, partials);
    k_sum  <<<1, 256, 0, stream>>>(partials, sumExp);
    k_accum<<<N_NODES / 4, 256, 0, stream>>>(off, sde, sumExp, xb, out);
    k_final<<<N_NODES / 64, 256, 0, stream>>>(x, fttb, ftb, out);
}